// Round 7
// baseline (534.041 us; speedup 1.0000x reference)
//
#include <hip/hip_runtime.h>

// Problem constants (fixed by the harness's setup_inputs)
#define NN 100000   // nodes
#define EE 1600000  // edges per relation
#define RR 4        // relations
#define FF 64       // feature size (in == out == 64)
#define NEDGE (RR * EE)

#define TB 256                        // nodes per bucket
#define NB ((NN + TB - 1) / TB)       // 391 buckets; bucket = dst >> 8
#define YB ((NN + 63) / 64)           // 1563 compute_y blocks
#define EPB 8192                      // edges per partition block
#define PB ((NEDGE + EPB - 1) / EPB)  // 782 partition blocks
#define IDXBITS 19                    // plane*NN+src < 400000 < 2^19
#define IDXMASK ((1 << IDXBITS) - 1)
#define CH 4096                       // recs per LDS chunk (32 KB)

// ---------------------------------------------------------------------------
// Fused: blocks [0,YB) compute Y[r] = inp @ W[r] (bf16 out);
//        blocks [YB,YB+PB) build per-block bucket histogram -> M row + btot.
__global__ __launch_bounds__(256) void fused_y_hist(const float* __restrict__ inp,
                                                    const float* __restrict__ W,
                                                    unsigned short* __restrict__ Y,
                                                    const int* __restrict__ dst,
                                                    int* __restrict__ M,
                                                    int* __restrict__ btot) {
    __shared__ __align__(16) char smem[64 * FF * sizeof(float)];   // 16 KB

    if (blockIdx.x < YB) {
        float* s_inp = (float*)smem;
        const int row0  = blockIdx.x * 64;
        const int nrows = min(64, NN - row0);
        {
            const float4* g  = reinterpret_cast<const float4*>(inp + (size_t)row0 * FF);
            float4*       s4 = reinterpret_cast<float4*>(s_inp);
            const int     nv4 = nrows * (FF / 4);
            for (int t = threadIdx.x; t < 64 * (FF / 4); t += 256)
                s4[t] = (t < nv4) ? g[t] : make_float4(0.f, 0.f, 0.f, 0.f);
        }
        __syncthreads();

        const int wid  = threadIdx.x >> 6;   // wave w computes relation w
        const int lane = threadIdx.x & 63;

        float wreg[FF];
        {
            const float* Wr = W + (size_t)wid * FF * FF + lane;
#pragma unroll
            for (int k = 0; k < FF; ++k) wreg[k] = Wr[(size_t)k * FF];
        }

        unsigned short* Yp = Y + ((size_t)wid * NN + row0) * FF + lane;
        for (int row = 0; row < nrows; ++row) {
            const float4* a4 = reinterpret_cast<const float4*>(s_inp + row * FF);
            float acc0 = 0.f, acc1 = 0.f, acc2 = 0.f, acc3 = 0.f;
#pragma unroll
            for (int k4 = 0; k4 < FF / 4; ++k4) {
                float4 a = a4[k4];  // wave-uniform -> LDS broadcast
                acc0 = fmaf(a.x, wreg[4 * k4 + 0], acc0);
                acc1 = fmaf(a.y, wreg[4 * k4 + 1], acc1);
                acc2 = fmaf(a.z, wreg[4 * k4 + 2], acc2);
                acc3 = fmaf(a.w, wreg[4 * k4 + 3], acc3);
            }
            const float s = (acc0 + acc1) + (acc2 + acc3);
            unsigned int u = __float_as_uint(s);
            u += 0x7FFFu + ((u >> 16) & 1u);          // round-to-nearest-even
            Yp[(size_t)row * FF] = (unsigned short)(u >> 16);
        }
    } else {
        int* h = (int*)smem;
        const int p = blockIdx.x - YB;
        for (int i = threadIdx.x; i < NB; i += 256) h[i] = 0;
        __syncthreads();
        const int base = p * EPB;
        const int n    = min(EPB, NEDGE - base);
        for (int t = threadIdx.x; t < n; t += 256)
            atomicAdd(&h[dst[base + t] >> 8], 1);
        __syncthreads();
        int* row = M + (size_t)p * NB;
        for (int i = threadIdx.x; i < NB; i += 256) {
            const int c = h[i];
            row[i] = c;
            if (c) atomicAdd(&btot[i], c);
        }
    }
}

// Exclusive scan of the NB(=391) bucket totals -> bbase[NB+1]; cursor copy.
__global__ __launch_bounds__(512) void scan_kernel(const int* __restrict__ btot,
                                                   int* __restrict__ bbase,
                                                   int* __restrict__ cursor) {
    __shared__ int s[512];
    const int tid = threadIdx.x;
    const int v   = (tid < NB) ? btot[tid] : 0;
    s[tid] = v;
    __syncthreads();
    for (int d = 1; d < 512; d <<= 1) {
        int t = (tid >= d) ? s[tid - d] : 0;
        __syncthreads();
        s[tid] += t;
        __syncthreads();
    }
    if (tid < NB) {
        const int ex = s[tid] - v;
        bbase[tid]  = ex;
        cursor[tid] = ex;
    }
    if (tid == 0) bbase[NB] = NEDGE;
}

// Pass C: single dst pass. Counts come from M row; each (block,bucket) slice
// is reserved with ONE global atomicAdd; records placed via LDS sub-cursors.
// rec.x = (dst_low8 << 19) | (plane*NN + src), rec.y = val bits.
__global__ __launch_bounds__(256) void passC_scatter(const int* __restrict__ src,
                                                     const int* __restrict__ dst,
                                                     const float* __restrict__ val,
                                                     const int* __restrict__ M,
                                                     int* __restrict__ cursor,
                                                     int2* __restrict__ recs) {
    __shared__ int h[NB];
    __shared__ int sbase[NB];
    const int p = blockIdx.x;
    {
        const int* row = M + (size_t)p * NB;
        for (int i = threadIdx.x; i < NB; i += 256) {
            const int c = row[i];
            h[i] = 0;
            if (c) sbase[i] = atomicAdd(&cursor[i], c);
        }
    }
    __syncthreads();
    const int base = p * EPB;
    const int n    = min(EPB, NEDGE - base);
    for (int t = threadIdx.x; t < n; t += 256) {
        const int e     = base + t;
        const int d     = dst[e];
        const int b     = d >> 8;
        const int plane = e / EE;                 // const-div -> magic mul
        const int idx   = atomicAdd(&h[b], 1);
        recs[sbase[b] + idx] = make_int2(((d & (TB - 1)) << IDXBITS) | (plane * NN + src[e]),
                                         __float_as_int(val[e]));
    }
}

// Fused sort+gather: one block per 256-node bucket. Chunk loop: load <=CH recs
// -> LDS counting sort by node (4-wave shfl scan) -> wave-per-node register-
// accumulating gather. acc[32] persists across chunks; coalesced store + bias.
__global__ __launch_bounds__(512, 4) void sort_gather(const int* __restrict__ bbase,
                                                      const int2* __restrict__ recs,
                                                      const unsigned short* __restrict__ Y,
                                                      const float* __restrict__ bias,
                                                      float* __restrict__ out) {
    __shared__ int2 srec[CH];        // 32 KB
    __shared__ int  h[TB];
    __shared__ int  sc[TB];
    __shared__ int  ctot[4];

    const int b    = blockIdx.x;
    const int tid  = threadIdx.x;
    const int wid  = tid >> 6;       // 8 waves; wave owns 32 local nodes
    const int lane = tid & 63;
    const int beg  = bbase[b];
    const int end  = bbase[b + 1];

    const float bl = bias[lane] + bias[FF + lane] + bias[2 * FF + lane] + bias[3 * FF + lane];

    float acc[32];
#pragma unroll
    for (int i = 0; i < 32; ++i) acc[i] = 0.f;

    for (int cbeg = beg; cbeg < end; cbeg += CH) {
        const int m = min(CH, end - cbeg);

        if (tid < TB) h[tid] = 0;
        __syncthreads();

        // load chunk + rank (register indices compile-time constant)
        int2 my[CH / 512];
        int  rk[CH / 512];
#pragma unroll
        for (int j = 0; j < CH / 512; ++j) {
            const int i = tid + j * 512;
            if (i < m) {
                my[j] = recs[cbeg + i];
                rk[j] = atomicAdd(&h[my[j].x >> IDXBITS], 1);
            }
        }
        __syncthreads();

        // inclusive scan of h[0..255]: 4 waves shfl-scan 64 each + chunk offsets
        int v = 0;
        if (tid < TB) {
            v = h[tid];
#pragma unroll
            for (int d = 1; d < 64; d <<= 1) {
                const int t = __shfl_up(v, d, 64);
                if ((tid & 63) >= d) v += t;
            }
            if ((tid & 63) == 63) ctot[tid >> 6] = v;
        }
        __syncthreads();
        if (tid < TB) {
            int off = 0;
#pragma unroll
            for (int c = 0; c < 3; ++c)
                if ((tid >> 6) > c) off += ctot[c];
            sc[tid] = v + off;
        }
        __syncthreads();

        // scatter into LDS in per-node order
#pragma unroll
        for (int j = 0; j < CH / 512; ++j) {
            const int i = tid + j * 512;
            if (i < m) {
                const int node = my[j].x >> IDXBITS;
                srec[sc[node] - h[node] + rk[j]] = my[j];
            }
        }
        __syncthreads();

        // gather: wave wid owns local nodes [wid*32, wid*32+32)
#define YLD(R) __uint_as_float(((unsigned int)Y[(size_t)((R).x & IDXMASK) * FF + lane]) << 16)
#pragma unroll
        for (int ni = 0; ni < 32; ++ni) {
            const int node = wid * 32 + ni;
            const int s1   = sc[node];
            int       e    = s1 - h[node];
            float     a    = acc[ni];
            for (; e + 8 <= s1; e += 8) {
                const int2 r0 = srec[e],     r1 = srec[e + 1], r2 = srec[e + 2], r3 = srec[e + 3];
                const int2 r4 = srec[e + 4], r5 = srec[e + 5], r6 = srec[e + 6], r7 = srec[e + 7];
                const float y0 = YLD(r0), y1 = YLD(r1), y2 = YLD(r2), y3 = YLD(r3);
                const float y4 = YLD(r4), y5 = YLD(r5), y6 = YLD(r6), y7 = YLD(r7);
                a = fmaf(__int_as_float(r0.y), y0, a);
                a = fmaf(__int_as_float(r1.y), y1, a);
                a = fmaf(__int_as_float(r2.y), y2, a);
                a = fmaf(__int_as_float(r3.y), y3, a);
                a = fmaf(__int_as_float(r4.y), y4, a);
                a = fmaf(__int_as_float(r5.y), y5, a);
                a = fmaf(__int_as_float(r6.y), y6, a);
                a = fmaf(__int_as_float(r7.y), y7, a);
            }
            for (; e < s1; ++e) {
                const int2 r = srec[e];
                a = fmaf(__int_as_float(r.y), YLD(r), a);
            }
            acc[ni] = a;
        }
#undef YLD
        __syncthreads();   // LDS reused by next chunk
    }

    // store: 32 coalesced 256B rows per wave
#pragma unroll
    for (int ni = 0; ni < 32; ++ni) {
        const int g = b * TB + wid * 32 + ni;
        if (g < NN) out[(size_t)g * FF + lane] = acc[ni] + bl;
    }
}

// ---------------------------------------------------------------------------
// Fallback (round-1): f32 Y + atomic scatter straight to out.
__global__ __launch_bounds__(256) void init_out_kernel(const float* __restrict__ bias,
                                                       float* __restrict__ out) {
    int i = blockIdx.x * 256 + threadIdx.x;
    int j = i & (FF - 1);
    out[i] = bias[j] + bias[FF + j] + bias[2 * FF + j] + bias[3 * FF + j];
}

__global__ __launch_bounds__(256) void compute_y_f32(const float* __restrict__ inp,
                                                     const float* __restrict__ W,
                                                     float* __restrict__ Y) {
    __shared__ float s_inp[64 * FF];
    const int row0  = blockIdx.x * 64;
    const int nrows = min(64, NN - row0);
    {
        const float4* g  = reinterpret_cast<const float4*>(inp + (size_t)row0 * FF);
        float4*       s4 = reinterpret_cast<float4*>(s_inp);
        const int     nv4 = nrows * (FF / 4);
        for (int t = threadIdx.x; t < 64 * (FF / 4); t += 256)
            s4[t] = (t < nv4) ? g[t] : make_float4(0.f, 0.f, 0.f, 0.f);
    }
    __syncthreads();
    const int wid  = threadIdx.x >> 6;
    const int lane = threadIdx.x & 63;
    float wreg[FF];
    {
        const float* Wr = W + (size_t)wid * FF * FF + lane;
#pragma unroll
        for (int k = 0; k < FF; ++k) wreg[k] = Wr[(size_t)k * FF];
    }
    float* Yp = Y + ((size_t)wid * NN + row0) * FF + lane;
    for (int row = 0; row < nrows; ++row) {
        const float4* a4 = reinterpret_cast<const float4*>(s_inp + row * FF);
        float acc0 = 0.f, acc1 = 0.f, acc2 = 0.f, acc3 = 0.f;
#pragma unroll
        for (int k4 = 0; k4 < FF / 4; ++k4) {
            float4 a = a4[k4];
            acc0 = fmaf(a.x, wreg[4 * k4 + 0], acc0);
            acc1 = fmaf(a.y, wreg[4 * k4 + 1], acc1);
            acc2 = fmaf(a.z, wreg[4 * k4 + 2], acc2);
            acc3 = fmaf(a.w, wreg[4 * k4 + 3], acc3);
        }
        Yp[(size_t)row * FF] = (acc0 + acc1) + (acc2 + acc3);
    }
}

__global__ __launch_bounds__(256) void edge_scatter_kernel(const int* __restrict__ src,
                                                           const int* __restrict__ dst,
                                                           const float* __restrict__ val,
                                                           const float* __restrict__ Y,
                                                           float* __restrict__ out) {
    const int w = (blockIdx.x * 256 + threadIdx.x) >> 6;
    if (w >= NEDGE) return;
    const int   lane  = threadIdx.x & 63;
    const int   plane = w / EE;
    const float y     = Y[((size_t)(plane * NN + src[w])) * FF + lane];
    atomicAdd(out + (size_t)dst[w] * FF + lane, val[w] * y);
}

// ---------------------------------------------------------------------------
extern "C" void kernel_launch(void* const* d_in, const int* in_sizes, int n_in,
                              void* d_out, int out_size, void* d_ws, size_t ws_size,
                              hipStream_t stream) {
    const float* inp  = (const float*)d_in[0];
    const int*   src  = (const int*)d_in[1];
    const int*   dst  = (const int*)d_in[2];
    const float* val  = (const float*)d_in[3];
    const float* W    = (const float*)d_in[4];
    const float* bias = (const float*)d_in[5];
    float*       out  = (float*)d_out;
    char*        ws   = (char*)d_ws;

    // ws layout
    const size_t Y_OFF  = 0;
    const size_t Y_SZ   = (size_t)RR * NN * FF * sizeof(unsigned short);  // 51.2 MB
    const size_t R_OFF  = Y_OFF + Y_SZ;
    const size_t R_SZ   = (size_t)NEDGE * sizeof(int2);                   // 51.2 MB
    const size_t M_OFF  = R_OFF + R_SZ;
    const size_t M_SZ   = (size_t)PB * NB * sizeof(int);                  // 1.22 MB
    const size_t T_OFF  = M_OFF + M_SZ;
    const size_t T_SZ   = (size_t)NB * sizeof(int);
    const size_t BB_OFF = T_OFF + T_SZ;
    const size_t BB_SZ  = (size_t)(NB + 1) * sizeof(int);
    const size_t C_OFF  = BB_OFF + BB_SZ;
    const size_t C_SZ   = (size_t)NB * sizeof(int);
    const size_t TOTAL  = C_OFF + C_SZ;                                   // ~103.7 MB

    unsigned short* Ybf    = (unsigned short*)(ws + Y_OFF);
    int2*           recs   = (int2*)(ws + R_OFF);
    int*            M      = (int*)(ws + M_OFF);
    int*            btot   = (int*)(ws + T_OFF);
    int*            bbase  = (int*)(ws + BB_OFF);
    int*            cursor = (int*)(ws + C_OFF);

    if (ws_size >= TOTAL) {
        hipMemsetAsync(btot, 0, T_SZ, stream);
        fused_y_hist<<<YB + PB, 256, 0, stream>>>(inp, W, Ybf, dst, M, btot);
        scan_kernel<<<1, 512, 0, stream>>>(btot, bbase, cursor);
        passC_scatter<<<PB, 256, 0, stream>>>(src, dst, val, M, cursor, recs);
        sort_gather<<<NB, 512, 0, stream>>>(bbase, recs, Ybf, bias, out);
    } else {
        // Fallback: f32 Y + atomic scatter (round-1 path), needs 102.4 MB
        float* Yf = (float*)ws;
        init_out_kernel<<<(NN * FF) / 256, 256, 0, stream>>>(bias, out);
        compute_y_f32<<<(NN + 63) / 64, 256, 0, stream>>>(inp, W, Yf);
        edge_scatter_kernel<<<(NEDGE + 3) / 4, 256, 0, stream>>>(src, dst, val, Yf, out);
    }
}

// Round 8
// 459.783 us; speedup vs baseline: 1.1615x; 1.1615x over previous
//
#include <hip/hip_runtime.h>

// Problem constants (fixed by the harness's setup_inputs)
#define NN 100000   // nodes
#define EE 1600000  // edges per relation
#define RR 4        // relations
#define FF 64       // feature size (in == out == 64)
#define NEDGE (RR * EE)

#define NBC 391                       // coarse buckets (256 nodes; dst>>8)
#define FB 64                         // fine bucket = 64 nodes
#define NB2 (NBC * 4)                 // 1564 fine buckets (dst>>6)
#define YB ((NN + 63) / 64)           // 1563 Y-GEMM blocks
#define EPB 8192                      // edges per partition block
#define PB ((NEDGE + EPB - 1) / EPB)  // 782 partition blocks
#define IDXBITS 19                    // plane*NN+src < 400000 < 2^19
#define IDXMASK ((1 << IDXBITS) - 1)
#define CH 4608                       // recs per LDS chunk in sort_gather

// ---------------------------------------------------------------------------
// Fused: blocks [0,YB) compute Y[r] = inp @ W[r] (bf16 out);
// blocks [YB,YB+PB): FINE per-block histogram -> coarse M row + fine btot.
__global__ __launch_bounds__(256) void fused_y_hist(const float* __restrict__ inp,
                                                    const float* __restrict__ W,
                                                    unsigned short* __restrict__ Y,
                                                    const int* __restrict__ dst,
                                                    int* __restrict__ M,
                                                    int* __restrict__ btot) {
    __shared__ __align__(16) char smem[64 * FF * sizeof(float)];   // 16 KB

    if (blockIdx.x < YB) {
        float* s_inp = (float*)smem;
        const int row0  = blockIdx.x * 64;
        const int nrows = min(64, NN - row0);
        {
            const float4* g  = reinterpret_cast<const float4*>(inp + (size_t)row0 * FF);
            float4*       s4 = reinterpret_cast<float4*>(s_inp);
            const int     nv4 = nrows * (FF / 4);
            for (int t = threadIdx.x; t < 64 * (FF / 4); t += 256)
                s4[t] = (t < nv4) ? g[t] : make_float4(0.f, 0.f, 0.f, 0.f);
        }
        __syncthreads();

        const int wid  = threadIdx.x >> 6;   // wave w computes relation w
        const int lane = threadIdx.x & 63;

        float wreg[FF];
        {
            const float* Wr = W + (size_t)wid * FF * FF + lane;
#pragma unroll
            for (int k = 0; k < FF; ++k) wreg[k] = Wr[(size_t)k * FF];
        }

        unsigned short* Yp = Y + ((size_t)wid * NN + row0) * FF + lane;
        for (int row = 0; row < nrows; ++row) {
            const float4* a4 = reinterpret_cast<const float4*>(s_inp + row * FF);
            float acc0 = 0.f, acc1 = 0.f, acc2 = 0.f, acc3 = 0.f;
#pragma unroll
            for (int k4 = 0; k4 < FF / 4; ++k4) {
                float4 a = a4[k4];  // wave-uniform -> LDS broadcast
                acc0 = fmaf(a.x, wreg[4 * k4 + 0], acc0);
                acc1 = fmaf(a.y, wreg[4 * k4 + 1], acc1);
                acc2 = fmaf(a.z, wreg[4 * k4 + 2], acc2);
                acc3 = fmaf(a.w, wreg[4 * k4 + 3], acc3);
            }
            const float s = (acc0 + acc1) + (acc2 + acc3);
            unsigned int u = __float_as_uint(s);
            u += 0x7FFFu + ((u >> 16) & 1u);          // round-to-nearest-even
            Yp[(size_t)row * FF] = (unsigned short)(u >> 16);
        }
    } else {
        int* h = (int*)smem;                  // NB2 ints = 6.3 KB
        const int p = blockIdx.x - YB;
        for (int i = threadIdx.x; i < NB2; i += 256) h[i] = 0;
        __syncthreads();
        const int base = p * EPB;
        const int n    = min(EPB, NEDGE - base);
        for (int t = threadIdx.x; t < n; t += 256)
            atomicAdd(&h[dst[base + t] >> 6], 1);   // FINE bucket
        __syncthreads();
        int* row = M + (size_t)p * NBC;
        for (int i = threadIdx.x; i < NBC; i += 256)
            row[i] = h[4 * i] + h[4 * i + 1] + h[4 * i + 2] + h[4 * i + 3];
        for (int i = threadIdx.x; i < NB2; i += 256)
            if (h[i]) atomicAdd(&btot[i], h[i]);
    }
}

// Exclusive scan of NB2 fine totals -> bbase2[NB2+1]; coarse cursor init.
__global__ __launch_bounds__(1024) void scan_kernel(const int* __restrict__ btot,
                                                    int* __restrict__ bbase2,
                                                    int* __restrict__ cursorC) {
    __shared__ int s[1024];
    __shared__ int carry_s;
    const int tid = threadIdx.x;
    if (tid == 0) carry_s = 0;
    __syncthreads();
    for (int c = 0; c < NB2; c += 1024) {
        const int i = c + tid;
        const int v = (i < NB2) ? btot[i] : 0;
        s[tid] = v;
        __syncthreads();
        for (int d = 1; d < 1024; d <<= 1) {
            int t = (tid >= d) ? s[tid - d] : 0;
            __syncthreads();
            s[tid] += t;
            __syncthreads();
        }
        if (i < NB2) {
            const int ex = s[tid] - v + carry_s;
            bbase2[i] = ex;
            if ((i & 3) == 0) cursorC[i >> 2] = ex;   // coarse region start
        }
        __syncthreads();
        if (tid == 1023) carry_s += s[1023];
        __syncthreads();
    }
    if (tid == 0) bbase2[NB2] = NEDGE;
}

// Pass C (coarse): single dst pass. Counts from M row; each (block,bucket)
// slice reserved with ONE global atomicAdd; placement via LDS sub-cursors.
// rec.x = (dst_low8 << 19) | (plane*NN + src), rec.y = val bits.
__global__ __launch_bounds__(256) void passC_scatter(const int* __restrict__ src,
                                                     const int* __restrict__ dst,
                                                     const float* __restrict__ val,
                                                     const int* __restrict__ M,
                                                     int* __restrict__ cursorC,
                                                     int2* __restrict__ recs) {
    __shared__ int h[NBC];
    __shared__ int sbase[NBC];
    const int p = blockIdx.x;
    {
        const int* row = M + (size_t)p * NBC;
        for (int i = threadIdx.x; i < NBC; i += 256) {
            const int c = row[i];
            h[i] = 0;
            if (c) sbase[i] = atomicAdd(&cursorC[i], c);
        }
    }
    __syncthreads();
    const int base = p * EPB;
    const int n    = min(EPB, NEDGE - base);
    for (int t = threadIdx.x; t < n; t += 256) {
        const int e     = base + t;
        const int d     = dst[e];
        const int b     = d >> 8;
        const int plane = e / EE;                 // const-div -> magic mul
        const int idx   = atomicAdd(&h[b], 1);
        recs[sbase[b] + idx] = make_int2(((d & 255) << IDXBITS) | (plane * NN + src[e]),
                                         __float_as_int(val[e]));
    }
}

// Pass D: refine each coarse bucket into its 4 fine sub-buckets. One block
// per coarse bucket streams the region once; wave-ballot ranking gives 4
// contiguous write runs per wave (coalesced). Only LDS cursor atomics.
__global__ __launch_bounds__(1024) void passD_refine(const int* __restrict__ bbase2,
                                                     const int2* __restrict__ recs,
                                                     int2* __restrict__ recs2) {
    __shared__ int cur[4];
    const int b    = blockIdx.x;                  // coarse bucket
    const int tid  = threadIdx.x;
    const int lane = tid & 63;
    const int beg  = bbase2[4 * b];
    const int end  = bbase2[4 * b + 4];
    if (tid < 4) cur[tid] = bbase2[4 * b + tid];
    __syncthreads();

    const int iters = (end - beg + 1023) >> 10;
    for (int it = 0; it < iters; ++it) {
        const int  i     = beg + it * 1024 + tid;
        const bool valid = i < end;
        int2 r = valid ? recs[i] : make_int2(0, 0);
        const int k = (r.x >> (IDXBITS + 6)) & 3;   // fine sub-bucket
        unsigned long long mk = 0;
#pragma unroll
        for (int kk = 0; kk < 4; ++kk) {
            const unsigned long long m = __ballot(valid && (k == kk));
            if (valid && k == kk) mk = m;
        }
        if (valid) {
            const int leader = __ffsll(mk) - 1;
            int base = 0;
            if (lane == leader) base = atomicAdd(&cur[k], (int)__popcll(mk));
            base = __shfl(base, leader);
            const int rank = (int)__popcll(mk & ((1ULL << lane) - 1ULL));
            recs2[base + rank] = r;
        }
    }
}

// Fused sort+gather (proven 161us config): one block per 64-node fine bucket.
// Chunk loop: load <=CH recs -> LDS counting sort by node (wave-0 shfl scan)
// -> wave-per-node register gather. acc[8] persists; coalesced store + bias.
__global__ __launch_bounds__(512, 6) void sort_gather(const int* __restrict__ bbase2,
                                                      const int2* __restrict__ recs2,
                                                      const unsigned short* __restrict__ Y,
                                                      const float* __restrict__ bias,
                                                      float* __restrict__ out) {
    __shared__ int2 srec[CH];        // 36 KB
    __shared__ int  h[FB];
    __shared__ int  sc[FB];

    const int b    = blockIdx.x;     // fine bucket
    const int tid  = threadIdx.x;
    const int wid  = tid >> 6;       // 8 waves; wave handles 8 local nodes
    const int lane = tid & 63;
    const int beg  = bbase2[b];
    const int end  = bbase2[b + 1];

    const float bl = bias[lane] + bias[FF + lane] + bias[2 * FF + lane] + bias[3 * FF + lane];

    float acc[8];
#pragma unroll
    for (int i = 0; i < 8; ++i) acc[i] = 0.f;

    for (int cbeg = beg; cbeg < end; cbeg += CH) {
        const int m = min(CH, end - cbeg);

        if (tid < FB) h[tid] = 0;
        __syncthreads();

        // load chunk + rank (register indices compile-time constant)
        int2 my[CH / 512];
        int  rk[CH / 512];
#pragma unroll
        for (int j = 0; j < CH / 512; ++j) {
            const int i = tid + j * 512;
            if (i < m) {
                my[j] = recs2[cbeg + i];
                rk[j] = atomicAdd(&h[(my[j].x >> IDXBITS) & (FB - 1)], 1);
            }
        }
        __syncthreads();

        // inclusive scan of h[0..63] by wave 0 via shfl
        if (tid < FB) {
            int v = h[tid];
#pragma unroll
            for (int d = 1; d < FB; d <<= 1) {
                const int t = __shfl_up(v, d, 64);
                if (tid >= d) v += t;
            }
            sc[tid] = v;
        }
        __syncthreads();

        // scatter into LDS in per-node order
#pragma unroll
        for (int j = 0; j < CH / 512; ++j) {
            const int i = tid + j * 512;
            if (i < m) {
                const int node = (my[j].x >> IDXBITS) & (FB - 1);
                srec[sc[node] - h[node] + rk[j]] = my[j];
            }
        }
        __syncthreads();

        // gather: wave wid owns local nodes [wid*8, wid*8+8)
#define YLD(R) __uint_as_float(((unsigned int)Y[(size_t)((R).x & IDXMASK) * FF + lane]) << 16)
#pragma unroll
        for (int ni = 0; ni < 8; ++ni) {
            const int node = wid * 8 + ni;
            const int s1   = sc[node];
            int       e    = s1 - h[node];
            float     a    = acc[ni];
            for (; e + 8 <= s1; e += 8) {
                const int2 r0 = srec[e],     r1 = srec[e + 1], r2 = srec[e + 2], r3 = srec[e + 3];
                const int2 r4 = srec[e + 4], r5 = srec[e + 5], r6 = srec[e + 6], r7 = srec[e + 7];
                const float y0 = YLD(r0), y1 = YLD(r1), y2 = YLD(r2), y3 = YLD(r3);
                const float y4 = YLD(r4), y5 = YLD(r5), y6 = YLD(r6), y7 = YLD(r7);
                a = fmaf(__int_as_float(r0.y), y0, a);
                a = fmaf(__int_as_float(r1.y), y1, a);
                a = fmaf(__int_as_float(r2.y), y2, a);
                a = fmaf(__int_as_float(r3.y), y3, a);
                a = fmaf(__int_as_float(r4.y), y4, a);
                a = fmaf(__int_as_float(r5.y), y5, a);
                a = fmaf(__int_as_float(r6.y), y6, a);
                a = fmaf(__int_as_float(r7.y), y7, a);
            }
            for (; e < s1; ++e) {
                const int2 r = srec[e];
                a = fmaf(__int_as_float(r.y), YLD(r), a);
            }
            acc[ni] = a;
        }
#undef YLD
        __syncthreads();   // LDS reused by next chunk
    }

    // store: 8 coalesced 256B rows per wave
#pragma unroll
    for (int ni = 0; ni < 8; ++ni) {
        const int g = b * FB + wid * 8 + ni;
        if (g < NN) out[(size_t)g * FF + lane] = acc[ni] + bl;
    }
}

// ---------------------------------------------------------------------------
// Fallback (round-1): f32 Y + atomic scatter straight to out.
__global__ __launch_bounds__(256) void init_out_kernel(const float* __restrict__ bias,
                                                       float* __restrict__ out) {
    int i = blockIdx.x * 256 + threadIdx.x;
    int j = i & (FF - 1);
    out[i] = bias[j] + bias[FF + j] + bias[2 * FF + j] + bias[3 * FF + j];
}

__global__ __launch_bounds__(256) void compute_y_f32(const float* __restrict__ inp,
                                                     const float* __restrict__ W,
                                                     float* __restrict__ Y) {
    __shared__ float s_inp[64 * FF];
    const int row0  = blockIdx.x * 64;
    const int nrows = min(64, NN - row0);
    {
        const float4* g  = reinterpret_cast<const float4*>(inp + (size_t)row0 * FF);
        float4*       s4 = reinterpret_cast<float4*>(s_inp);
        const int     nv4 = nrows * (FF / 4);
        for (int t = threadIdx.x; t < 64 * (FF / 4); t += 256)
            s4[t] = (t < nv4) ? g[t] : make_float4(0.f, 0.f, 0.f, 0.f);
    }
    __syncthreads();
    const int wid  = threadIdx.x >> 6;
    const int lane = threadIdx.x & 63;
    float wreg[FF];
    {
        const float* Wr = W + (size_t)wid * FF * FF + lane;
#pragma unroll
        for (int k = 0; k < FF; ++k) wreg[k] = Wr[(size_t)k * FF];
    }
    float* Yp = Y + ((size_t)wid * NN + row0) * FF + lane;
    for (int row = 0; row < nrows; ++row) {
        const float4* a4 = reinterpret_cast<const float4*>(s_inp + row * FF);
        float acc0 = 0.f, acc1 = 0.f, acc2 = 0.f, acc3 = 0.f;
#pragma unroll
        for (int k4 = 0; k4 < FF / 4; ++k4) {
            float4 a = a4[k4];
            acc0 = fmaf(a.x, wreg[4 * k4 + 0], acc0);
            acc1 = fmaf(a.y, wreg[4 * k4 + 1], acc1);
            acc2 = fmaf(a.z, wreg[4 * k4 + 2], acc2);
            acc3 = fmaf(a.w, wreg[4 * k4 + 3], acc3);
        }
        Yp[(size_t)row * FF] = (acc0 + acc1) + (acc2 + acc3);
    }
}

__global__ __launch_bounds__(256) void edge_scatter_kernel(const int* __restrict__ src,
                                                           const int* __restrict__ dst,
                                                           const float* __restrict__ val,
                                                           const float* __restrict__ Y,
                                                           float* __restrict__ out) {
    const int w = (blockIdx.x * 256 + threadIdx.x) >> 6;
    if (w >= NEDGE) return;
    const int   lane  = threadIdx.x & 63;
    const int   plane = w / EE;
    const float y     = Y[((size_t)(plane * NN + src[w])) * FF + lane];
    atomicAdd(out + (size_t)dst[w] * FF + lane, val[w] * y);
}

// ---------------------------------------------------------------------------
extern "C" void kernel_launch(void* const* d_in, const int* in_sizes, int n_in,
                              void* d_out, int out_size, void* d_ws, size_t ws_size,
                              hipStream_t stream) {
    const float* inp  = (const float*)d_in[0];
    const int*   src  = (const int*)d_in[1];
    const int*   dst  = (const int*)d_in[2];
    const float* val  = (const float*)d_in[3];
    const float* W    = (const float*)d_in[4];
    const float* bias = (const float*)d_in[5];
    float*       out  = (float*)d_out;
    char*        ws   = (char*)d_ws;

    // ws layout (8B-aligned)
    const size_t Y_OFF  = 0;
    const size_t Y_SZ   = (size_t)RR * NN * FF * sizeof(unsigned short);  // 51.2 MB
    const size_t R_OFF  = Y_OFF + Y_SZ;
    const size_t R_SZ   = (size_t)NEDGE * sizeof(int2);                   // 51.2 MB
    const size_t R2_OFF = R_OFF + R_SZ;
    const size_t R2_SZ  = (size_t)NEDGE * sizeof(int2);                   // 51.2 MB
    const size_t M_OFF  = R2_OFF + R2_SZ;
    const size_t M_SZ   = (size_t)PB * NBC * sizeof(int);                 // 1.22 MB
    const size_t T_OFF  = M_OFF + M_SZ;
    const size_t T_SZ   = (size_t)NB2 * sizeof(int);
    const size_t B2_OFF = T_OFF + T_SZ;
    const size_t B2_SZ  = (size_t)(NB2 + 1) * sizeof(int);
    const size_t C_OFF  = B2_OFF + B2_SZ;
    const size_t C_SZ   = (size_t)NBC * sizeof(int);
    const size_t TOTAL  = C_OFF + C_SZ;                                   // ~154.8 MB

    unsigned short* Ybf     = (unsigned short*)(ws + Y_OFF);
    int2*           recs    = (int2*)(ws + R_OFF);
    int2*           recs2   = (int2*)(ws + R2_OFF);
    int*            M       = (int*)(ws + M_OFF);
    int*            btot    = (int*)(ws + T_OFF);
    int*            bbase2  = (int*)(ws + B2_OFF);
    int*            cursorC = (int*)(ws + C_OFF);

    if (ws_size >= TOTAL) {
        hipMemsetAsync(btot, 0, T_SZ, stream);
        fused_y_hist<<<YB + PB, 256, 0, stream>>>(inp, W, Ybf, dst, M, btot);
        scan_kernel<<<1, 1024, 0, stream>>>(btot, bbase2, cursorC);
        passC_scatter<<<PB, 256, 0, stream>>>(src, dst, val, M, cursorC, recs);
        passD_refine<<<NBC, 1024, 0, stream>>>(bbase2, recs, recs2);
        sort_gather<<<NB2, 512, 0, stream>>>(bbase2, recs2, Ybf, bias, out);
    } else {
        // Fallback: f32 Y + atomic scatter (round-1 path), needs 102.4 MB
        float* Yf = (float*)ws;
        init_out_kernel<<<(NN * FF) / 256, 256, 0, stream>>>(bias, out);
        compute_y_f32<<<(NN + 63) / 64, 256, 0, stream>>>(inp, W, Yf);
        edge_scatter_kernel<<<(NEDGE + 3) / 4, 256, 0, stream>>>(src, dst, val, Yf, out);
    }
}

// Round 9
// 421.993 us; speedup vs baseline: 1.2655x; 1.0896x over previous
//
#include <hip/hip_runtime.h>

// Problem constants (fixed by the harness's setup_inputs)
#define NN 100000   // nodes
#define EE 1600000  // edges per relation
#define RR 4        // relations
#define FF 64       // feature size (in == out == 64)
#define NEDGE (RR * EE)

#define NBC 391                       // coarse buckets (256 nodes; dst>>8)
#define FB 64                         // fine bucket = 64 nodes
#define NB2 (NBC * 4)                 // 1564 fine buckets (dst>>6)
#define YB ((NN + 63) / 64)           // 1563 Y-GEMM blocks
#define EPB 8192                      // edges per histogram block
#define PB ((NEDGE + EPB - 1) / EPB)  // 782 histogram blocks
#define PC_B 512                      // passC blocks (2 per CU)
#define PC_T 512                      // passC threads
#define SEG (NEDGE / PC_B)            // 12500 edges per passC block
#define IDXBITS 19                    // plane*NN+src < 400000 < 2^19
#define IDXMASK ((1 << IDXBITS) - 1)
#define CH 4608                       // recs per LDS chunk in sort_gather

// ---------------------------------------------------------------------------
// Fused: blocks [0,YB) compute Y[r] = inp @ W[r] (bf16 out);
// blocks [YB,YB+PB): FINE per-block histogram -> fine btot (for bbase2).
__global__ __launch_bounds__(256) void fused_y_hist(const float* __restrict__ inp,
                                                    const float* __restrict__ W,
                                                    unsigned short* __restrict__ Y,
                                                    const int* __restrict__ dst,
                                                    int* __restrict__ btot) {
    __shared__ __align__(16) char smem[64 * FF * sizeof(float)];   // 16 KB

    if (blockIdx.x < YB) {
        float* s_inp = (float*)smem;
        const int row0  = blockIdx.x * 64;
        const int nrows = min(64, NN - row0);
        {
            const float4* g  = reinterpret_cast<const float4*>(inp + (size_t)row0 * FF);
            float4*       s4 = reinterpret_cast<float4*>(s_inp);
            const int     nv4 = nrows * (FF / 4);
            for (int t = threadIdx.x; t < 64 * (FF / 4); t += 256)
                s4[t] = (t < nv4) ? g[t] : make_float4(0.f, 0.f, 0.f, 0.f);
        }
        __syncthreads();

        const int wid  = threadIdx.x >> 6;   // wave w computes relation w
        const int lane = threadIdx.x & 63;

        float wreg[FF];
        {
            const float* Wr = W + (size_t)wid * FF * FF + lane;
#pragma unroll
            for (int k = 0; k < FF; ++k) wreg[k] = Wr[(size_t)k * FF];
        }

        unsigned short* Yp = Y + ((size_t)wid * NN + row0) * FF + lane;
        for (int row = 0; row < nrows; ++row) {
            const float4* a4 = reinterpret_cast<const float4*>(s_inp + row * FF);
            float acc0 = 0.f, acc1 = 0.f, acc2 = 0.f, acc3 = 0.f;
#pragma unroll
            for (int k4 = 0; k4 < FF / 4; ++k4) {
                float4 a = a4[k4];  // wave-uniform -> LDS broadcast
                acc0 = fmaf(a.x, wreg[4 * k4 + 0], acc0);
                acc1 = fmaf(a.y, wreg[4 * k4 + 1], acc1);
                acc2 = fmaf(a.z, wreg[4 * k4 + 2], acc2);
                acc3 = fmaf(a.w, wreg[4 * k4 + 3], acc3);
            }
            const float s = (acc0 + acc1) + (acc2 + acc3);
            unsigned int u = __float_as_uint(s);
            u += 0x7FFFu + ((u >> 16) & 1u);          // round-to-nearest-even
            Yp[(size_t)row * FF] = (unsigned short)(u >> 16);
        }
    } else {
        int* h = (int*)smem;                  // NB2 ints = 6.3 KB
        const int p = blockIdx.x - YB;
        for (int i = threadIdx.x; i < NB2; i += 256) h[i] = 0;
        __syncthreads();
        const int base = p * EPB;
        const int n    = min(EPB, NEDGE - base);
        for (int t = threadIdx.x; t < n; t += 256)
            atomicAdd(&h[dst[base + t] >> 6], 1);   // FINE bucket
        __syncthreads();
        for (int i = threadIdx.x; i < NB2; i += 256)
            if (h[i]) atomicAdd(&btot[i], h[i]);
    }
}

// Exclusive scan of NB2 fine totals -> bbase2[NB2+1]; coarse cursor init.
__global__ __launch_bounds__(1024) void scan_kernel(const int* __restrict__ btot,
                                                    int* __restrict__ bbase2,
                                                    int* __restrict__ cursorC) {
    __shared__ int s[1024];
    __shared__ int carry_s;
    const int tid = threadIdx.x;
    if (tid == 0) carry_s = 0;
    __syncthreads();
    for (int c = 0; c < NB2; c += 1024) {
        const int i = c + tid;
        const int v = (i < NB2) ? btot[i] : 0;
        s[tid] = v;
        __syncthreads();
        for (int d = 1; d < 1024; d <<= 1) {
            int t = (tid >= d) ? s[tid - d] : 0;
            __syncthreads();
            s[tid] += t;
            __syncthreads();
        }
        if (i < NB2) {
            const int ex = s[tid] - v + carry_s;
            bbase2[i] = ex;
            if ((i & 3) == 0) cursorC[i >> 2] = ex;   // coarse region start
        }
        __syncthreads();
        if (tid == 1023) carry_s += s[1023];
        __syncthreads();
    }
    if (tid == 0) bbase2[NB2] = NEDGE;
}

// Pass C (coarse, self-counting, low block count): each block owns a
// contiguous SEG-edge segment. Pass 1 counts per coarse bucket in LDS;
// one global atomicAdd per non-empty bucket reserves the slice; pass 2
// places records (dst re-read hits L2). Few concurrent writers -> slice
// lines stay L2-resident until filled -> full-line streaming writes.
// rec.x = (dst_low8 << 19) | (plane*NN + src), rec.y = val bits.
__global__ __launch_bounds__(PC_T) void passC_scatter(const int* __restrict__ src,
                                                      const int* __restrict__ dst,
                                                      const float* __restrict__ val,
                                                      int* __restrict__ cursorC,
                                                      int2* __restrict__ recs) {
    __shared__ int h[NBC];
    __shared__ int sbase[NBC];
    const int base = blockIdx.x * SEG;
    const int tid  = threadIdx.x;

    for (int i = tid; i < NBC; i += PC_T) h[i] = 0;
    __syncthreads();
    for (int t = tid; t < SEG; t += PC_T)
        atomicAdd(&h[dst[base + t] >> 8], 1);
    __syncthreads();
    for (int i = tid; i < NBC; i += PC_T) {
        const int c = h[i];
        if (c) sbase[i] = atomicAdd(&cursorC[i], c);
        h[i] = 0;
    }
    __syncthreads();
    for (int t = tid; t < SEG; t += PC_T) {
        const int e     = base + t;
        const int d     = dst[e];
        const int b     = d >> 8;
        const int plane = e / EE;                 // const-div -> magic mul
        const int idx   = atomicAdd(&h[b], 1);
        recs[sbase[b] + idx] = make_int2(((d & 255) << IDXBITS) | (plane * NN + src[e]),
                                         __float_as_int(val[e]));
    }
}

// Pass D: refine each coarse bucket into its 4 fine sub-buckets. One block
// per coarse bucket streams the region once; wave-ballot ranking gives 4
// contiguous write runs per wave (coalesced). Only LDS cursor atomics.
__global__ __launch_bounds__(1024) void passD_refine(const int* __restrict__ bbase2,
                                                     const int2* __restrict__ recs,
                                                     int2* __restrict__ recs2) {
    __shared__ int cur[4];
    const int b    = blockIdx.x;                  // coarse bucket
    const int tid  = threadIdx.x;
    const int lane = tid & 63;
    const int beg  = bbase2[4 * b];
    const int end  = bbase2[4 * b + 4];
    if (tid < 4) cur[tid] = bbase2[4 * b + tid];
    __syncthreads();

    const int iters = (end - beg + 1023) >> 10;
    for (int it = 0; it < iters; ++it) {
        const int  i     = beg + it * 1024 + tid;
        const bool valid = i < end;
        int2 r = valid ? recs[i] : make_int2(0, 0);
        const int k = (r.x >> (IDXBITS + 6)) & 3;   // fine sub-bucket
        unsigned long long mk = 0;
#pragma unroll
        for (int kk = 0; kk < 4; ++kk) {
            const unsigned long long m = __ballot(valid && (k == kk));
            if (valid && k == kk) mk = m;
        }
        if (valid) {
            const int leader = __ffsll(mk) - 1;
            int base = 0;
            if (lane == leader) base = atomicAdd(&cur[k], (int)__popcll(mk));
            base = __shfl(base, leader);
            const int rank = (int)__popcll(mk & ((1ULL << lane) - 1ULL));
            recs2[base + rank] = r;
        }
    }
}

// Fused sort+gather (proven config): one block per 64-node fine bucket.
// Chunk loop: load <=CH recs -> LDS counting sort by node (wave-0 shfl scan)
// -> wave-per-node register gather. acc[8] persists; coalesced store + bias.
__global__ __launch_bounds__(512, 6) void sort_gather(const int* __restrict__ bbase2,
                                                      const int2* __restrict__ recs2,
                                                      const unsigned short* __restrict__ Y,
                                                      const float* __restrict__ bias,
                                                      float* __restrict__ out) {
    __shared__ int2 srec[CH];        // 36 KB
    __shared__ int  h[FB];
    __shared__ int  sc[FB];

    const int b    = blockIdx.x;     // fine bucket
    const int tid  = threadIdx.x;
    const int wid  = tid >> 6;       // 8 waves; wave handles 8 local nodes
    const int lane = tid & 63;
    const int beg  = bbase2[b];
    const int end  = bbase2[b + 1];

    const float bl = bias[lane] + bias[FF + lane] + bias[2 * FF + lane] + bias[3 * FF + lane];

    float acc[8];
#pragma unroll
    for (int i = 0; i < 8; ++i) acc[i] = 0.f;

    for (int cbeg = beg; cbeg < end; cbeg += CH) {
        const int m = min(CH, end - cbeg);

        if (tid < FB) h[tid] = 0;
        __syncthreads();

        // load chunk + rank (register indices compile-time constant)
        int2 my[CH / 512];
        int  rk[CH / 512];
#pragma unroll
        for (int j = 0; j < CH / 512; ++j) {
            const int i = tid + j * 512;
            if (i < m) {
                my[j] = recs2[cbeg + i];
                rk[j] = atomicAdd(&h[(my[j].x >> IDXBITS) & (FB - 1)], 1);
            }
        }
        __syncthreads();

        // inclusive scan of h[0..63] by wave 0 via shfl
        if (tid < FB) {
            int v = h[tid];
#pragma unroll
            for (int d = 1; d < FB; d <<= 1) {
                const int t = __shfl_up(v, d, 64);
                if (tid >= d) v += t;
            }
            sc[tid] = v;
        }
        __syncthreads();

        // scatter into LDS in per-node order
#pragma unroll
        for (int j = 0; j < CH / 512; ++j) {
            const int i = tid + j * 512;
            if (i < m) {
                const int node = (my[j].x >> IDXBITS) & (FB - 1);
                srec[sc[node] - h[node] + rk[j]] = my[j];
            }
        }
        __syncthreads();

        // gather: wave wid owns local nodes [wid*8, wid*8+8)
#define YLD(R) __uint_as_float(((unsigned int)Y[(size_t)((R).x & IDXMASK) * FF + lane]) << 16)
#pragma unroll
        for (int ni = 0; ni < 8; ++ni) {
            const int node = wid * 8 + ni;
            const int s1   = sc[node];
            int       e    = s1 - h[node];
            float     a    = acc[ni];
            for (; e + 8 <= s1; e += 8) {
                const int2 r0 = srec[e],     r1 = srec[e + 1], r2 = srec[e + 2], r3 = srec[e + 3];
                const int2 r4 = srec[e + 4], r5 = srec[e + 5], r6 = srec[e + 6], r7 = srec[e + 7];
                const float y0 = YLD(r0), y1 = YLD(r1), y2 = YLD(r2), y3 = YLD(r3);
                const float y4 = YLD(r4), y5 = YLD(r5), y6 = YLD(r6), y7 = YLD(r7);
                a = fmaf(__int_as_float(r0.y), y0, a);
                a = fmaf(__int_as_float(r1.y), y1, a);
                a = fmaf(__int_as_float(r2.y), y2, a);
                a = fmaf(__int_as_float(r3.y), y3, a);
                a = fmaf(__int_as_float(r4.y), y4, a);
                a = fmaf(__int_as_float(r5.y), y5, a);
                a = fmaf(__int_as_float(r6.y), y6, a);
                a = fmaf(__int_as_float(r7.y), y7, a);
            }
            for (; e < s1; ++e) {
                const int2 r = srec[e];
                a = fmaf(__int_as_float(r.y), YLD(r), a);
            }
            acc[ni] = a;
        }
#undef YLD
        __syncthreads();   // LDS reused by next chunk
    }

    // store: 8 coalesced 256B rows per wave
#pragma unroll
    for (int ni = 0; ni < 8; ++ni) {
        const int g = b * FB + wid * 8 + ni;
        if (g < NN) out[(size_t)g * FF + lane] = acc[ni] + bl;
    }
}

// ---------------------------------------------------------------------------
// Fallback (round-1): f32 Y + atomic scatter straight to out.
__global__ __launch_bounds__(256) void init_out_kernel(const float* __restrict__ bias,
                                                       float* __restrict__ out) {
    int i = blockIdx.x * 256 + threadIdx.x;
    int j = i & (FF - 1);
    out[i] = bias[j] + bias[FF + j] + bias[2 * FF + j] + bias[3 * FF + j];
}

__global__ __launch_bounds__(256) void compute_y_f32(const float* __restrict__ inp,
                                                     const float* __restrict__ W,
                                                     float* __restrict__ Y) {
    __shared__ float s_inp[64 * FF];
    const int row0  = blockIdx.x * 64;
    const int nrows = min(64, NN - row0);
    {
        const float4* g  = reinterpret_cast<const float4*>(inp + (size_t)row0 * FF);
        float4*       s4 = reinterpret_cast<float4*>(s_inp);
        const int     nv4 = nrows * (FF / 4);
        for (int t = threadIdx.x; t < 64 * (FF / 4); t += 256)
            s4[t] = (t < nv4) ? g[t] : make_float4(0.f, 0.f, 0.f, 0.f);
    }
    __syncthreads();
    const int wid  = threadIdx.x >> 6;
    const int lane = threadIdx.x & 63;
    float wreg[FF];
    {
        const float* Wr = W + (size_t)wid * FF * FF + lane;
#pragma unroll
        for (int k = 0; k < FF; ++k) wreg[k] = Wr[(size_t)k * FF];
    }
    float* Yp = Y + ((size_t)wid * NN + row0) * FF + lane;
    for (int row = 0; row < nrows; ++row) {
        const float4* a4 = reinterpret_cast<const float4*>(s_inp + row * FF);
        float acc0 = 0.f, acc1 = 0.f, acc2 = 0.f, acc3 = 0.f;
#pragma unroll
        for (int k4 = 0; k4 < FF / 4; ++k4) {
            float4 a = a4[k4];
            acc0 = fmaf(a.x, wreg[4 * k4 + 0], acc0);
            acc1 = fmaf(a.y, wreg[4 * k4 + 1], acc1);
            acc2 = fmaf(a.z, wreg[4 * k4 + 2], acc2);
            acc3 = fmaf(a.w, wreg[4 * k4 + 3], acc3);
        }
        Yp[(size_t)row * FF] = (acc0 + acc1) + (acc2 + acc3);
    }
}

__global__ __launch_bounds__(256) void edge_scatter_kernel(const int* __restrict__ src,
                                                           const int* __restrict__ dst,
                                                           const float* __restrict__ val,
                                                           const float* __restrict__ Y,
                                                           float* __restrict__ out) {
    const int w = (blockIdx.x * 256 + threadIdx.x) >> 6;
    if (w >= NEDGE) return;
    const int   lane  = threadIdx.x & 63;
    const int   plane = w / EE;
    const float y     = Y[((size_t)(plane * NN + src[w])) * FF + lane];
    atomicAdd(out + (size_t)dst[w] * FF + lane, val[w] * y);
}

// ---------------------------------------------------------------------------
extern "C" void kernel_launch(void* const* d_in, const int* in_sizes, int n_in,
                              void* d_out, int out_size, void* d_ws, size_t ws_size,
                              hipStream_t stream) {
    const float* inp  = (const float*)d_in[0];
    const int*   src  = (const int*)d_in[1];
    const int*   dst  = (const int*)d_in[2];
    const float* val  = (const float*)d_in[3];
    const float* W    = (const float*)d_in[4];
    const float* bias = (const float*)d_in[5];
    float*       out  = (float*)d_out;
    char*        ws   = (char*)d_ws;

    // ws layout (8B-aligned)
    const size_t Y_OFF  = 0;
    const size_t Y_SZ   = (size_t)RR * NN * FF * sizeof(unsigned short);  // 51.2 MB
    const size_t R_OFF  = Y_OFF + Y_SZ;
    const size_t R_SZ   = (size_t)NEDGE * sizeof(int2);                   // 51.2 MB
    const size_t R2_OFF = R_OFF + R_SZ;
    const size_t R2_SZ  = (size_t)NEDGE * sizeof(int2);                   // 51.2 MB
    const size_t T_OFF  = R2_OFF + R2_SZ;
    const size_t T_SZ   = (size_t)NB2 * sizeof(int);
    const size_t B2_OFF = T_OFF + T_SZ;
    const size_t B2_SZ  = (size_t)(NB2 + 1) * sizeof(int) + 4;
    const size_t C_OFF  = B2_OFF + B2_SZ;
    const size_t C_SZ   = (size_t)NBC * sizeof(int);
    const size_t TOTAL  = C_OFF + C_SZ;                                   // ~153.6 MB

    unsigned short* Ybf     = (unsigned short*)(ws + Y_OFF);
    int2*           recs    = (int2*)(ws + R_OFF);
    int2*           recs2   = (int2*)(ws + R2_OFF);
    int*            btot    = (int*)(ws + T_OFF);
    int*            bbase2  = (int*)(ws + B2_OFF);
    int*            cursorC = (int*)(ws + C_OFF);

    if (ws_size >= TOTAL) {
        hipMemsetAsync(btot, 0, T_SZ, stream);
        fused_y_hist<<<YB + PB, 256, 0, stream>>>(inp, W, Ybf, dst, btot);
        scan_kernel<<<1, 1024, 0, stream>>>(btot, bbase2, cursorC);
        passC_scatter<<<PC_B, PC_T, 0, stream>>>(src, dst, val, cursorC, recs);
        passD_refine<<<NBC, 1024, 0, stream>>>(bbase2, recs, recs2);
        sort_gather<<<NB2, 512, 0, stream>>>(bbase2, recs2, Ybf, bias, out);
    } else {
        // Fallback: f32 Y + atomic scatter (round-1 path), needs 102.4 MB
        float* Yf = (float*)ws;
        init_out_kernel<<<(NN * FF) / 256, 256, 0, stream>>>(bias, out);
        compute_y_f32<<<(NN + 63) / 64, 256, 0, stream>>>(inp, W, Yf);
        edge_scatter_kernel<<<(NEDGE + 3) / 4, 256, 0, stream>>>(src, dst, val, Yf, out);
    }
}

// Round 10
// 379.899 us; speedup vs baseline: 1.4057x; 1.1108x over previous
//
#include <hip/hip_runtime.h>

// Problem constants (fixed by the harness's setup_inputs)
#define NN 100000   // nodes
#define EE 1600000  // edges per relation
#define RR 4        // relations
#define FF 64       // feature size (in == out == 64)
#define NEDGE (RR * EE)

#define FB 64                         // fine bucket = 64 nodes
#define NB2 ((NN + FB - 1) / FB)      // 1563 fine buckets (dst>>6)
#define YB ((NN + 63) / 64)           // 1563 Y-GEMM blocks
#define EPB 8192                      // edges per histogram block
#define PB ((NEDGE + EPB - 1) / EPB)  // 782 histogram blocks
#define PC_B 512                      // passC blocks (2 per CU)
#define PC_T 512                      // passC threads
#define SEG (NEDGE / PC_B)            // 12500 edges per passC block
#define IDXBITS 19                    // plane*NN+src < 400000 < 2^19
#define IDXMASK ((1 << IDXBITS) - 1)
#define CH 4608                       // recs per LDS chunk in sort_gather

// ---------------------------------------------------------------------------
// Fused: blocks [0,YB) compute Y[r] = inp @ W[r] (bf16 out);
// blocks [YB,YB+PB): FINE per-block histogram -> fine btot (for bbase2).
__global__ __launch_bounds__(256) void fused_y_hist(const float* __restrict__ inp,
                                                    const float* __restrict__ W,
                                                    unsigned short* __restrict__ Y,
                                                    const int* __restrict__ dst,
                                                    int* __restrict__ btot) {
    __shared__ __align__(16) char smem[64 * FF * sizeof(float)];   // 16 KB

    if (blockIdx.x < YB) {
        float* s_inp = (float*)smem;
        const int row0  = blockIdx.x * 64;
        const int nrows = min(64, NN - row0);
        {
            const float4* g  = reinterpret_cast<const float4*>(inp + (size_t)row0 * FF);
            float4*       s4 = reinterpret_cast<float4*>(s_inp);
            const int     nv4 = nrows * (FF / 4);
            for (int t = threadIdx.x; t < 64 * (FF / 4); t += 256)
                s4[t] = (t < nv4) ? g[t] : make_float4(0.f, 0.f, 0.f, 0.f);
        }
        __syncthreads();

        const int wid  = threadIdx.x >> 6;   // wave w computes relation w
        const int lane = threadIdx.x & 63;

        float wreg[FF];
        {
            const float* Wr = W + (size_t)wid * FF * FF + lane;
#pragma unroll
            for (int k = 0; k < FF; ++k) wreg[k] = Wr[(size_t)k * FF];
        }

        unsigned short* Yp = Y + ((size_t)wid * NN + row0) * FF + lane;
        for (int row = 0; row < nrows; ++row) {
            const float4* a4 = reinterpret_cast<const float4*>(s_inp + row * FF);
            float acc0 = 0.f, acc1 = 0.f, acc2 = 0.f, acc3 = 0.f;
#pragma unroll
            for (int k4 = 0; k4 < FF / 4; ++k4) {
                float4 a = a4[k4];  // wave-uniform -> LDS broadcast
                acc0 = fmaf(a.x, wreg[4 * k4 + 0], acc0);
                acc1 = fmaf(a.y, wreg[4 * k4 + 1], acc1);
                acc2 = fmaf(a.z, wreg[4 * k4 + 2], acc2);
                acc3 = fmaf(a.w, wreg[4 * k4 + 3], acc3);
            }
            const float s = (acc0 + acc1) + (acc2 + acc3);
            unsigned int u = __float_as_uint(s);
            u += 0x7FFFu + ((u >> 16) & 1u);          // round-to-nearest-even
            Yp[(size_t)row * FF] = (unsigned short)(u >> 16);
        }
    } else {
        int* h = (int*)smem;                  // NB2 ints = 6.3 KB
        const int p = blockIdx.x - YB;
        for (int i = threadIdx.x; i < NB2; i += 256) h[i] = 0;
        __syncthreads();
        const int base = p * EPB;
        const int n    = min(EPB, NEDGE - base);
        for (int t = threadIdx.x; t < n; t += 256)
            atomicAdd(&h[dst[base + t] >> 6], 1);   // FINE bucket
        __syncthreads();
        for (int i = threadIdx.x; i < NB2; i += 256)
            if (h[i]) atomicAdd(&btot[i], h[i]);
    }
}

// Exclusive scan of NB2 fine totals -> bbase2[NB2+1]; fine cursor init.
__global__ __launch_bounds__(1024) void scan_kernel(const int* __restrict__ btot,
                                                    int* __restrict__ bbase2,
                                                    int* __restrict__ cursorF) {
    __shared__ int s[1024];
    __shared__ int carry_s;
    const int tid = threadIdx.x;
    if (tid == 0) carry_s = 0;
    __syncthreads();
    for (int c = 0; c < NB2; c += 1024) {
        const int i = c + tid;
        const int v = (i < NB2) ? btot[i] : 0;
        s[tid] = v;
        __syncthreads();
        for (int d = 1; d < 1024; d <<= 1) {
            int t = (tid >= d) ? s[tid - d] : 0;
            __syncthreads();
            s[tid] += t;
            __syncthreads();
        }
        if (i < NB2) {
            const int ex = s[tid] - v + carry_s;
            bbase2[i]  = ex;
            cursorF[i] = ex;
        }
        __syncthreads();
        if (tid == 1023) carry_s += s[1023];
        __syncthreads();
    }
    if (tid == 0) bbase2[NB2] = NEDGE;
}

// Pass C (FINE, self-counting): each block owns a contiguous SEG-edge
// segment. Pass 1 counts per fine bucket in LDS; one global atomicAdd per
// non-empty bucket reserves the slice; pass 2 places records (dst re-read
// hits L2). rec.x = (dst_low8 << 19) | (plane*NN + src), rec.y = val bits.
__global__ __launch_bounds__(PC_T) void passC_scatter(const int* __restrict__ src,
                                                      const int* __restrict__ dst,
                                                      const float* __restrict__ val,
                                                      int* __restrict__ cursorF,
                                                      int2* __restrict__ recs) {
    __shared__ int h[NB2];
    __shared__ int sbase[NB2];
    const int base = blockIdx.x * SEG;
    const int tid  = threadIdx.x;

    for (int i = tid; i < NB2; i += PC_T) h[i] = 0;
    __syncthreads();
    for (int t = tid; t < SEG; t += PC_T)
        atomicAdd(&h[dst[base + t] >> 6], 1);
    __syncthreads();
    for (int i = tid; i < NB2; i += PC_T) {
        const int c = h[i];
        if (c) sbase[i] = atomicAdd(&cursorF[i], c);
        h[i] = 0;
    }
    __syncthreads();
    for (int t = tid; t < SEG; t += PC_T) {
        const int e     = base + t;
        const int d     = dst[e];
        const int b     = d >> 6;
        const int plane = e / EE;                 // const-div -> magic mul
        const int idx   = atomicAdd(&h[b], 1);
        recs[sbase[b] + idx] = make_int2(((d & 255) << IDXBITS) | (plane * NN + src[e]),
                                         __float_as_int(val[e]));
    }
}

// Fused sort+gather (proven config): one block per 64-node fine bucket.
// Chunk loop: load <=CH recs -> LDS counting sort by node (wave-0 shfl scan)
// -> wave-per-node register gather. acc[8] persists; coalesced store + bias.
__global__ __launch_bounds__(512, 6) void sort_gather(const int* __restrict__ bbase2,
                                                      const int2* __restrict__ recs,
                                                      const unsigned short* __restrict__ Y,
                                                      const float* __restrict__ bias,
                                                      float* __restrict__ out) {
    __shared__ int2 srec[CH];        // 36 KB
    __shared__ int  h[FB];
    __shared__ int  sc[FB];

    const int b    = blockIdx.x;     // fine bucket
    const int tid  = threadIdx.x;
    const int wid  = tid >> 6;       // 8 waves; wave handles 8 local nodes
    const int lane = tid & 63;
    const int beg  = bbase2[b];
    const int end  = bbase2[b + 1];

    const float bl = bias[lane] + bias[FF + lane] + bias[2 * FF + lane] + bias[3 * FF + lane];

    float acc[8];
#pragma unroll
    for (int i = 0; i < 8; ++i) acc[i] = 0.f;

    for (int cbeg = beg; cbeg < end; cbeg += CH) {
        const int m = min(CH, end - cbeg);

        if (tid < FB) h[tid] = 0;
        __syncthreads();

        // load chunk + rank (register indices compile-time constant)
        int2 my[CH / 512];
        int  rk[CH / 512];
#pragma unroll
        for (int j = 0; j < CH / 512; ++j) {
            const int i = tid + j * 512;
            if (i < m) {
                my[j] = recs[cbeg + i];
                rk[j] = atomicAdd(&h[(my[j].x >> IDXBITS) & (FB - 1)], 1);
            }
        }
        __syncthreads();

        // inclusive scan of h[0..63] by wave 0 via shfl
        if (tid < FB) {
            int v = h[tid];
#pragma unroll
            for (int d = 1; d < FB; d <<= 1) {
                const int t = __shfl_up(v, d, 64);
                if (tid >= d) v += t;
            }
            sc[tid] = v;
        }
        __syncthreads();

        // scatter into LDS in per-node order
#pragma unroll
        for (int j = 0; j < CH / 512; ++j) {
            const int i = tid + j * 512;
            if (i < m) {
                const int node = (my[j].x >> IDXBITS) & (FB - 1);
                srec[sc[node] - h[node] + rk[j]] = my[j];
            }
        }
        __syncthreads();

        // gather: wave wid owns local nodes [wid*8, wid*8+8)
#define YLD(R) __uint_as_float(((unsigned int)Y[(size_t)((R).x & IDXMASK) * FF + lane]) << 16)
#pragma unroll
        for (int ni = 0; ni < 8; ++ni) {
            const int node = wid * 8 + ni;
            const int s1   = sc[node];
            int       e    = s1 - h[node];
            float     a    = acc[ni];
            for (; e + 8 <= s1; e += 8) {
                const int2 r0 = srec[e],     r1 = srec[e + 1], r2 = srec[e + 2], r3 = srec[e + 3];
                const int2 r4 = srec[e + 4], r5 = srec[e + 5], r6 = srec[e + 6], r7 = srec[e + 7];
                const float y0 = YLD(r0), y1 = YLD(r1), y2 = YLD(r2), y3 = YLD(r3);
                const float y4 = YLD(r4), y5 = YLD(r5), y6 = YLD(r6), y7 = YLD(r7);
                a = fmaf(__int_as_float(r0.y), y0, a);
                a = fmaf(__int_as_float(r1.y), y1, a);
                a = fmaf(__int_as_float(r2.y), y2, a);
                a = fmaf(__int_as_float(r3.y), y3, a);
                a = fmaf(__int_as_float(r4.y), y4, a);
                a = fmaf(__int_as_float(r5.y), y5, a);
                a = fmaf(__int_as_float(r6.y), y6, a);
                a = fmaf(__int_as_float(r7.y), y7, a);
            }
            for (; e < s1; ++e) {
                const int2 r = srec[e];
                a = fmaf(__int_as_float(r.y), YLD(r), a);
            }
            acc[ni] = a;
        }
#undef YLD
        __syncthreads();   // LDS reused by next chunk
    }

    // store: 8 coalesced 256B rows per wave
#pragma unroll
    for (int ni = 0; ni < 8; ++ni) {
        const int g = b * FB + wid * 8 + ni;
        if (g < NN) out[(size_t)g * FF + lane] = acc[ni] + bl;
    }
}

// ---------------------------------------------------------------------------
// Fallback (round-1): f32 Y + atomic scatter straight to out.
__global__ __launch_bounds__(256) void init_out_kernel(const float* __restrict__ bias,
                                                       float* __restrict__ out) {
    int i = blockIdx.x * 256 + threadIdx.x;
    int j = i & (FF - 1);
    out[i] = bias[j] + bias[FF + j] + bias[2 * FF + j] + bias[3 * FF + j];
}

__global__ __launch_bounds__(256) void compute_y_f32(const float* __restrict__ inp,
                                                     const float* __restrict__ W,
                                                     float* __restrict__ Y) {
    __shared__ float s_inp[64 * FF];
    const int row0  = blockIdx.x * 64;
    const int nrows = min(64, NN - row0);
    {
        const float4* g  = reinterpret_cast<const float4*>(inp + (size_t)row0 * FF);
        float4*       s4 = reinterpret_cast<float4*>(s_inp);
        const int     nv4 = nrows * (FF / 4);
        for (int t = threadIdx.x; t < 64 * (FF / 4); t += 256)
            s4[t] = (t < nv4) ? g[t] : make_float4(0.f, 0.f, 0.f, 0.f);
    }
    __syncthreads();
    const int wid  = threadIdx.x >> 6;
    const int lane = threadIdx.x & 63;
    float wreg[FF];
    {
        const float* Wr = W + (size_t)wid * FF * FF + lane;
#pragma unroll
        for (int k = 0; k < FF; ++k) wreg[k] = Wr[(size_t)k * FF];
    }
    float* Yp = Y + ((size_t)wid * NN + row0) * FF + lane;
    for (int row = 0; row < nrows; ++row) {
        const float4* a4 = reinterpret_cast<const float4*>(s_inp + row * FF);
        float acc0 = 0.f, acc1 = 0.f, acc2 = 0.f, acc3 = 0.f;
#pragma unroll
        for (int k4 = 0; k4 < FF / 4; ++k4) {
            float4 a = a4[k4];
            acc0 = fmaf(a.x, wreg[4 * k4 + 0], acc0);
            acc1 = fmaf(a.y, wreg[4 * k4 + 1], acc1);
            acc2 = fmaf(a.z, wreg[4 * k4 + 2], acc2);
            acc3 = fmaf(a.w, wreg[4 * k4 + 3], acc3);
        }
        Yp[(size_t)row * FF] = (acc0 + acc1) + (acc2 + acc3);
    }
}

__global__ __launch_bounds__(256) void edge_scatter_kernel(const int* __restrict__ src,
                                                           const int* __restrict__ dst,
                                                           const float* __restrict__ val,
                                                           const float* __restrict__ Y,
                                                           float* __restrict__ out) {
    const int w = (blockIdx.x * 256 + threadIdx.x) >> 6;
    if (w >= NEDGE) return;
    const int   lane  = threadIdx.x & 63;
    const int   plane = w / EE;
    const float y     = Y[((size_t)(plane * NN + src[w])) * FF + lane];
    atomicAdd(out + (size_t)dst[w] * FF + lane, val[w] * y);
}

// ---------------------------------------------------------------------------
extern "C" void kernel_launch(void* const* d_in, const int* in_sizes, int n_in,
                              void* d_out, int out_size, void* d_ws, size_t ws_size,
                              hipStream_t stream) {
    const float* inp  = (const float*)d_in[0];
    const int*   src  = (const int*)d_in[1];
    const int*   dst  = (const int*)d_in[2];
    const float* val  = (const float*)d_in[3];
    const float* W    = (const float*)d_in[4];
    const float* bias = (const float*)d_in[5];
    float*       out  = (float*)d_out;
    char*        ws   = (char*)d_ws;

    // ws layout (8B-aligned)
    const size_t Y_OFF  = 0;
    const size_t Y_SZ   = (size_t)RR * NN * FF * sizeof(unsigned short);  // 51.2 MB
    const size_t R_OFF  = Y_OFF + Y_SZ;
    const size_t R_SZ   = (size_t)NEDGE * sizeof(int2);                   // 51.2 MB
    const size_t T_OFF  = R_OFF + R_SZ;
    const size_t T_SZ   = (size_t)NB2 * sizeof(int);
    const size_t B2_OFF = T_OFF + T_SZ;
    const size_t B2_SZ  = (size_t)(NB2 + 1) * sizeof(int) + 4;
    const size_t C_OFF  = B2_OFF + B2_SZ;
    const size_t C_SZ   = (size_t)NB2 * sizeof(int);
    const size_t TOTAL  = C_OFF + C_SZ;                                   // ~102.4 MB

    unsigned short* Ybf     = (unsigned short*)(ws + Y_OFF);
    int2*           recs    = (int2*)(ws + R_OFF);
    int*            btot    = (int*)(ws + T_OFF);
    int*            bbase2  = (int*)(ws + B2_OFF);
    int*            cursorF = (int*)(ws + C_OFF);

    if (ws_size >= TOTAL) {
        hipMemsetAsync(btot, 0, T_SZ, stream);
        fused_y_hist<<<YB + PB, 256, 0, stream>>>(inp, W, Ybf, dst, btot);
        scan_kernel<<<1, 1024, 0, stream>>>(btot, bbase2, cursorF);
        passC_scatter<<<PC_B, PC_T, 0, stream>>>(src, dst, val, cursorF, recs);
        sort_gather<<<NB2, 512, 0, stream>>>(bbase2, recs, Ybf, bias, out);
    } else {
        // Fallback: f32 Y + atomic scatter (round-1 path), needs 102.4 MB
        float* Yf = (float*)ws;
        init_out_kernel<<<(NN * FF) / 256, 256, 0, stream>>>(bias, out);
        compute_y_f32<<<(NN + 63) / 64, 256, 0, stream>>>(inp, W, Yf);
        edge_scatter_kernel<<<(NEDGE + 3) / 4, 256, 0, stream>>>(src, dst, val, Yf, out);
    }
}